// Round 16
// baseline (289.199 us; speedup 1.0000x reference)
//
#include <hip/hip_runtime.h>
#include <hip/hip_bf16.h>
#include <math.h>

// Problem constants
#define BB 64
#define SS 2048
#define IN_ 256
#define MSLOT 8
#define HH 8
#define HD_ 64
#define MM 512
#define NG_ 1024

typedef __attribute__((ext_vector_type(8))) short short8;
typedef __attribute__((ext_vector_type(8))) unsigned short ushort8;
typedef __attribute__((ext_vector_type(4))) unsigned short ushort4v;
typedef __attribute__((ext_vector_type(4))) float f32x4;
typedef __attribute__((ext_vector_type(16))) float f32x16;
typedef unsigned long long u64;
typedef unsigned int u32;

__device__ __forceinline__ unsigned short f2bf(float f) {
    unsigned int u = __builtin_bit_cast(unsigned int, f);
    u += 0x7fff + ((u >> 16) & 1);   // round-to-nearest-even
    return (unsigned short)(u >> 16);
}

// HW packed f32x2 -> bf16x2 (RNE), lo=a hi=b
__device__ __forceinline__ u32 f2bf_pk(float a, float b) {
    u32 r;
    asm("v_cvt_pk_bf16_f32 %0, %1, %2" : "=v"(r) : "v"(a), "v"(b));
    return r;
}

// sortable key: larger value -> larger key; equal value -> smaller idx -> larger key
__device__ __forceinline__ u64 score_key(float v, int idx) {
    u32 x = __float_as_uint(v);
    u32 fk = (x & 0x80000000u) ? ~x : (x | 0x80000000u);
    return ((u64)fk << 32) | (u32)(~(u32)idx);
}
__device__ __forceinline__ float key_val(u64 k) {
    u32 fk = (u32)(k >> 32);
    u32 x = (fk & 0x80000000u) ? (fk & 0x7FFFFFFFu) : ~fk;
    return __uint_as_float(x);
}
__device__ __forceinline__ int key_idx(u64 k) { return (int)(~(u32)k); }

__device__ __forceinline__ void merge3(u64& a0, u64& a1, u64& a2, u64 b0, u64 b1, u64 b2) {
    bool t0 = a0 >= b0;
    u64 m0 = t0 ? a0 : b0;
    u64 a0x = t0 ? a1 : a0, a1x = t0 ? a2 : a1;
    u64 b0x = t0 ? b0 : b1, b1x = t0 ? b1 : b2;
    bool t1 = a0x >= b0x;
    u64 m1 = t1 ? a0x : b0x;
    u64 a0y = t1 ? a1x : a0x;
    u64 b0y = t1 ? b0x : b1x;
    bool t2 = a0y >= b0y;
    u64 m2 = t2 ? a0y : b0y;
    a0 = m0; a1 = m1; a2 = m2;
}

__device__ __forceinline__ void merge3_shfl(u64& k0, u64& k1, u64& k2, int off) {
    u64 b0 = __shfl_xor(k0, off);
    u64 b1 = __shfl_xor(k1, off);
    u64 b2 = __shfl_xor(k2, off);
    merge3(k0, k1, k2, b0, b1, b2);
}

__device__ __forceinline__ float block_sum256(float v, float* red) {
    int t = threadIdx.x;
    red[t] = v; __syncthreads();
    for (int s = 128; s > 0; s >>= 1) {
        if (t < s) red[t] += red[t + s];
        __syncthreads();
    }
    float r = red[0];
    __syncthreads();
    return r;
}

// ---- LDS tile staging: 64 rows x 256 cols bf16, 16B-chunk XOR(r&15) swizzle
__device__ __forceinline__ void stage_tile_f32cvt(unsigned short* lds,
                                                  const float* __restrict__ src,
                                                  int t) {
#pragma unroll
    for (int it = 0; it < 8; ++it) {
        int c = t + it * 256;
        int r = c >> 5, ch = c & 31;
        const float* p = src + (size_t)r * 256 + ch * 8;
        float4 f0 = *(const float4*)p;
        float4 f1 = *(const float4*)(p + 4);
        uint4 v;
        v.x = f2bf_pk(f0.x, f0.y);
        v.y = f2bf_pk(f0.z, f0.w);
        v.z = f2bf_pk(f1.x, f1.y);
        v.w = f2bf_pk(f1.z, f1.w);
        int sch = ch ^ (r & 15);
        *(uint4*)(lds + r * 256 + sch * 8) = v;
    }
}

__device__ __forceinline__ short8 frag_ld(const unsigned short* lds, int row, int chunk) {
    int sch = chunk ^ (row & 15);
    return *(const short8*)(lds + row * 256 + sch * 8);
}

__device__ __forceinline__ short8 frag_ld512(const unsigned short* lds, int row, int chunk) {
    int sch = chunk ^ (row & 7);
    return *(const short8*)(lds + row * 512 + sch * 8);
}

// ---------------- K_PRE: fused weights GEMM + q GEMM + repacks (independent prep work)
__global__ __launch_bounds__(256) void k_pre(const float* __restrict__ Wi,
                                             const float* __restrict__ Wk,
                                             const float* __restrict__ Wv,
                                             const float* __restrict__ bi,
                                             const float* __restrict__ bv,
                                             const float* __restrict__ memory,
                                             const float* __restrict__ Wq,
                                             const float* __restrict__ bq,
                                             const float* __restrict__ Wmlp,
                                             float* __restrict__ WikT,
                                             float* __restrict__ Wiv,
                                             float* __restrict__ bvf,
                                             float* __restrict__ q,
                                             unsigned short* __restrict__ WiTf,
                                             unsigned short* __restrict__ tm,
                                             unsigned short* __restrict__ WmlpTb) {
    __shared__ float As[64 * 33];   // 2112 floats
    __shared__ float Bs[32 * 65];   // 2080 floats
    int blk = blockIdx.x;
    int t = threadIdx.x;

    if (blk < 256) {
        // fused-weights GEMM: WikT / Wiv
        int which = blk >> 7;
        int rem = blk & 127;
        int ot = rem >> 3, it = rem & 7;
        int o0 = ot * 32, i0 = it * 32;
        const float* W = which ? Wv : Wk;
        int tx = t & 15, ty = t >> 4;
        float acc[2][2] = {{0.f, 0.f}, {0.f, 0.f}};
        for (int jc = 0; jc < 512; jc += 64) {
            __syncthreads();
#pragma unroll
            for (int k = 0; k < 8; ++k) {
                int idx = t + k * 256;
                int jl = idx >> 5, ol = idx & 31;
                As[jl * 33 + ol] = W[(jc + jl) * 512 + o0 + ol];
            }
#pragma unroll
            for (int k = 0; k < 8; ++k) {
                int idx = t + k * 256;
                int il = idx >> 6, jl = idx & 63;
                Bs[il * 65 + jl] = Wi[(i0 + il) * 512 + jc + jl];
            }
            __syncthreads();
#pragma unroll 4
            for (int jl = 0; jl < 64; ++jl) {
                float a0 = As[jl * 33 + ty], a1 = As[jl * 33 + ty + 16];
                float b0 = Bs[tx * 65 + jl], b1 = Bs[(tx + 16) * 65 + jl];
                acc[0][0] += a0 * b0; acc[0][1] += a0 * b1;
                acc[1][0] += a1 * b0; acc[1][1] += a1 * b1;
            }
        }
#pragma unroll
        for (int m = 0; m < 2; ++m)
#pragma unroll
            for (int n = 0; n < 2; ++n) {
                int o = o0 + ty + 16 * m, i = i0 + tx + 16 * n;
                if (which) Wiv[i * 512 + o] = acc[m][n];
                else       WikT[o * 256 + i] = acc[m][n];
            }
    } else if (blk < 258) {
        int o = (blk - 256) * 256 + t;
        float acc = bv[o];
        for (int j = 0; j < 512; ++j) acc += bi[j] * Wv[j * 512 + o];
        bvf[o] = acc;
    } else if (blk < 514) {
        // q GEMM: q = memory@Wq + bq. Am -> Bs (32*65), Bq -> As (64*33)
        int qb = blk - 258;
        int bt = qb >> 4, ot2 = qb & 15;
        int b0 = bt * 32, o0 = ot2 * 32;
        int tx = t & 15, ty = t >> 4;
        float acc[2][2] = {{0.f, 0.f}, {0.f, 0.f}};
        for (int jc = 0; jc < 512; jc += 64) {
            __syncthreads();
#pragma unroll
            for (int k = 0; k < 8; ++k) {
                int idx = t + k * 256;
                int bl = idx >> 6, jl = idx & 63;
                Bs[bl * 65 + jl] = memory[(b0 + bl) * 512 + jc + jl];
            }
#pragma unroll
            for (int k = 0; k < 8; ++k) {
                int idx = t + k * 256;
                int jl = idx >> 5, ol = idx & 31;
                As[jl * 33 + ol] = Wq[(jc + jl) * 512 + o0 + ol];
            }
            __syncthreads();
#pragma unroll 4
            for (int jl = 0; jl < 64; ++jl) {
                float a0 = Bs[ty * 65 + jl], a1 = Bs[(ty + 16) * 65 + jl];
                float b0v = As[jl * 33 + tx], b1v = As[jl * 33 + tx + 16];
                acc[0][0] += a0 * b0v; acc[0][1] += a0 * b1v;
                acc[1][0] += a1 * b0v; acc[1][1] += a1 * b1v;
            }
        }
#pragma unroll
        for (int m = 0; m < 2; ++m)
#pragma unroll
            for (int n = 0; n < 2; ++n) {
                int bms = b0 + ty + 16 * m, o = o0 + tx + 16 * n;
                q[bms * 512 + o] = acc[m][n] + bq[o];
            }
    } else {
        int pb = blk - 514;
        if (pb < 512) {
            int idx = pb * 256 + t;
            int e = idx & 7, l = (idx >> 3) & 63, ks = (idx >> 9) & 15, dtg = idx >> 13;
            int d = dtg * 32 + (l & 31);
            int k = ks * 16 + (l >> 5) * 8 + e;
            WiTf[idx] = f2bf(Wi[k * 512 + d]);
        } else if (pb < 768) {
            int i = ((pb - 512) * 256 + t) * 4;
            float4 v = *(const float4*)(memory + i);
            ushort4v o;
            o[0] = f2bf(tanhf(v.x)); o[1] = f2bf(tanhf(v.y));
            o[2] = f2bf(tanhf(v.z)); o[3] = f2bf(tanhf(v.w));
            *(ushort4v*)(tm + i) = o;
        } else {
            int o = pb - 768;   // 0..511
#pragma unroll
            for (int kk = 0; kk < 2; ++kk) {
                int k = kk * 256 + t;
                WmlpTb[o * 512 + k] = f2bf(Wmlp[k * 512 + o]);
            }
        }
    }
}

// ---------------- K1c: P[b,hm,i] (bf16)
__global__ __launch_bounds__(256) void k_p(const float* __restrict__ q,
                                           const float* __restrict__ WikT,
                                           unsigned short* __restrict__ Pb) {
    int blk = blockIdx.x;           // b*64 + hm
    int b = blk >> 6, hm = blk & 63;
    int h = hm >> 3, ms = hm & 7;
    int t = threadIdx.x;
    __shared__ float qv[64];
    if (t < 64) qv[t] = q[(b * 8 + ms) * 512 + h * 64 + t];
    __syncthreads();
    float acc = 0.f;
    for (int d = 0; d < 64; ++d) acc += qv[d] * WikT[(h * 64 + d) * 256 + t];
    Pb[blk * 256 + t] = f2bf(acc);
}

// ---------------- K_BIG v9: Sl overlays Il (32.8 KB LDS -> 4 blocks/CU).
// scores -> sval regs; gimean; barrier; stash; barrier; stats.
__global__ __launch_bounds__(256, 4) void k_big(const float* __restrict__ inputs,
                                                const unsigned short* __restrict__ Pb,
                                                const unsigned short* __restrict__ WiTf,
                                                const float* __restrict__ bi,
                                                const float* __restrict__ rw,
                                                uint4* __restrict__ statA,
                                                uint4* __restrict__ statB,
                                                float* __restrict__ giaccp) {
    __shared__ unsigned short Il[64 * 256];   // 32 KB; Sl overlays after gimean
    float* Sl = (float*)Il;                   // [64][65] f32 score stash (16.6 KB)
    int t = threadIdx.x;
    int hw = blockIdx.x;                      // 0..2047
    int L = (hw & 7) * 256 + (hw >> 3);
    int b = L >> 5, stile = L & 31;
    int l = t & 63, w = t >> 6;
    int l31 = l & 31, hi = l >> 5;
    int sh = w & 1, dh = w >> 1;

    stage_tile_f32cvt(Il, inputs + ((size_t)b * SS + stile * 64) * IN_, t);
    __syncthreads();

    // ---- scores (32x32x16): A = P rows (hm = dh*32+l31, L2), B = Il frags. 2x8 chains.
    float sval[16];
    {
        f32x16 s0 = {0.f,0.f,0.f,0.f,0.f,0.f,0.f,0.f,0.f,0.f,0.f,0.f,0.f,0.f,0.f,0.f};
        f32x16 s1 = {0.f,0.f,0.f,0.f,0.f,0.f,0.f,0.f,0.f,0.f,0.f,0.f,0.f,0.f,0.f,0.f};
        const unsigned short* pbase = Pb + ((size_t)(b * 64 + dh * 32 + l31)) * 256;
#pragma unroll
        for (int ks = 0; ks < 8; ++ks) {
            short8 pf0 = *(const short8*)(pbase + ks * 16 + hi * 8);
            short8 il0 = frag_ld(Il, sh * 32 + l31, ks * 2 + hi);
            s0 = __builtin_amdgcn_mfma_f32_32x32x16_bf16(pf0, il0, s0, 0, 0, 0);
            short8 pf1 = *(const short8*)(pbase + (ks + 8) * 16 + hi * 8);
            short8 il1 = frag_ld(Il, sh * 32 + l31, (ks + 8) * 2 + hi);
            s1 = __builtin_amdgcn_mfma_f32_32x32x16_bf16(pf1, il1, s1, 0, 0, 0);
        }
#pragma unroll
        for (int r = 0; r < 16; ++r) sval[r] = s0[r] + s1[r];
    }

    // ---- gimean (32x32x16): A = Il frags, B = WiTf (d cols). One dtg per grp, 2 chains.
#pragma unroll 1
    for (int grp = 0; grp < 8; ++grp) {
        int dtg = dh * 8 + grp;
        f32x16 ga = {0.f,0.f,0.f,0.f,0.f,0.f,0.f,0.f,0.f,0.f,0.f,0.f,0.f,0.f,0.f,0.f};
        f32x16 gb = {0.f,0.f,0.f,0.f,0.f,0.f,0.f,0.f,0.f,0.f,0.f,0.f,0.f,0.f,0.f,0.f};
#pragma unroll
        for (int ks = 0; ks < 8; ++ks) {
            short8 il0 = frag_ld(Il, sh * 32 + l31, ks * 2 + hi);
            short8 wf0 = *(const short8*)(WiTf + ((size_t)(dtg * 16 + ks) * 64 + l) * 8);
            ga = __builtin_amdgcn_mfma_f32_32x32x16_bf16(il0, wf0, ga, 0, 0, 0);
            short8 il1 = frag_ld(Il, sh * 32 + l31, (ks + 8) * 2 + hi);
            short8 wf1 = *(const short8*)(WiTf + ((size_t)(dtg * 16 + ks + 8) * 64 + l) * 8);
            gb = __builtin_amdgcn_mfma_f32_32x32x16_bf16(il1, wf1, gb, 0, 0, 0);
        }
        int d = dtg * 32 + l31;
        float bid = bi[d], rwd = rw[d];
        float rs = 0.f;
#pragma unroll
        for (int r = 0; r < 16; ++r)
            rs += fmaxf(rwd * (ga[r] + gb[r] + bid), 0.f);
        rs += __shfl_xor(rs, 32);
        if (hi == 0)
            giaccp[((size_t)(stile * 2 + sh) * 64 + b) * 512 + d] = rs;
    }
    __syncthreads();   // all Il fragment reads complete

    // ---- stash scores into Sl (overlaying Il): row = (r&3)+8*(r>>2)+4*hi, col = sh*32+l31
#pragma unroll
    for (int r = 0; r < 16; ++r) {
        int hm = dh * 32 + (r & 3) + 8 * (r >> 2) + 4 * hi;
        Sl[hm * 65 + sh * 32 + l31] = sval[r];
    }
    __syncthreads();

    // ---- stats: thread t -> row = t>>2, s-chunk (t&3)*16..+15
    int row = t >> 2, cq = t & 3;
    float v[16];
#pragma unroll
    for (int i = 0; i < 16; ++i) v[i] = Sl[row * 65 + cq * 16 + i];

    u64 k0 = 0, k1 = 0, k2 = 0;
#pragma unroll
    for (int i = 0; i < 16; ++i) {
        u64 key = score_key(v[i], stile * 64 + cq * 16 + i);
        bool g0 = key > k0, g1 = key > k1, g2 = key > k2;
        k2 = g1 ? k1 : (g2 ? key : k2);
        k1 = g0 ? k0 : (g1 ? key : k1);
        k0 = g0 ? key : k0;
    }
    merge3_shfl(k0, k1, k2, 1);
    merge3_shfl(k0, k1, k2, 2);

    float m = key_val(k0);
    float se = 0.f;
#pragma unroll
    for (int i = 0; i < 16; ++i) se += expf(v[i] - m);
    se += __shfl_xor(se, 1);
    se += __shfl_xor(se, 2);

    if (cq == 0) {
        int grow = (b * 64 + row) * 32 + stile;
        statA[grow] = make_uint4(__float_as_uint(se), (u32)(k0 >> 32), (u32)k0, (u32)(k1 >> 32));
        statB[grow] = make_uint4((u32)k1, (u32)(k2 >> 32), (u32)k2, 0u);
    }
}

// ---------------- K_MID: combine (blocks 0..1023) + gatein (1024..1279)
__global__ __launch_bounds__(256) void k_mid(const uint4* __restrict__ statA,
                                             const uint4* __restrict__ statB,
                                             const float* __restrict__ giaccp,
                                             const float* __restrict__ Wr,
                                             const float* __restrict__ br,
                                             float* __restrict__ topk_p,
                                             int* __restrict__ topk_idx,
                                             float* __restrict__ gate_in) {
    __shared__ float gm[512];
    int blk = blockIdx.x;
    int t = threadIdx.x;
    if (blk < 1024) {
        int row = blk * 4 + (t >> 6);
        int l = t & 63;
        float s_c = 0.f, m_c = 0.f;
        u64 k0 = 0, k1 = 0, k2 = 0;
        if (l < 32) {
            uint4 A = statA[row * 32 + l];
            uint4 Bv = statB[row * 32 + l];
            s_c = __uint_as_float(A.x);
            k0 = ((u64)A.y << 32) | A.z;
            k1 = ((u64)A.w << 32) | Bv.x;
            k2 = ((u64)Bv.y << 32) | Bv.z;
            m_c = key_val(k0);
        }
        merge3_shfl(k0, k1, k2, 1);
        merge3_shfl(k0, k1, k2, 2);
        merge3_shfl(k0, k1, k2, 4);
        merge3_shfl(k0, k1, k2, 8);
        merge3_shfl(k0, k1, k2, 16);

        float M = key_val(k0);
        float S = (l < 32) ? s_c * expf(m_c - M) : 0.f;
#pragma unroll
        for (int off = 1; off <= 16; off <<= 1) S += __shfl_xor(S, off);

        if (l == 0) {
            u64 ks[3] = {k0, k1, k2};
#pragma unroll
            for (int r = 0; r < 3; ++r) {
                topk_p[row * 3 + r] = expf(key_val(ks[r]) - M) / S;
                topk_idx[row * 3 + r] = key_idx(ks[r]);
            }
        }
    } else {
        int gb = blk - 1024;
        int b = gb >> 2, ot = gb & 3;
        int o = ot * 256 + t;
        float s0 = 0.f, s1 = 0.f;
        for (int st = 0; st < 64; ++st) {
            s0 += giaccp[((size_t)st * 64 + b) * 512 + t];
            s1 += giaccp[((size_t)st * 64 + b) * 512 + t + 256];
        }
        gm[t]       = s0 * (1.0f / 2048.0f);
        gm[t + 256] = s1 * (1.0f / 2048.0f);
        __syncthreads();
        float acc = br[o];
#pragma unroll 8
        for (int d = 0; d < 512; ++d) acc += gm[d] * Wr[d * 1024 + o];
        gate_in[b * 1024 + o] = acc;
    }
}

// ---------------- K_POST: gates MFMA (blocks 0..255) + att+LN1 (256..767)
__global__ __launch_bounds__(256) void k_post(const unsigned short* __restrict__ tmem_b,
                                              const float* __restrict__ Wg,
                                              const float* __restrict__ gate_in,
                                              const float* __restrict__ fb,
                                              const float* __restrict__ ib,
                                              float* __restrict__ sg,
                                              const float* __restrict__ inputs,
                                              const float* __restrict__ Wiv,
                                              const float* __restrict__ bvf,
                                              const float* __restrict__ topk_p,
                                              const int* __restrict__ topk_idx,
                                              const float* __restrict__ memory,
                                              const float* __restrict__ g1,
                                              const float* __restrict__ b1,
                                              float* __restrict__ mem1) {
    __shared__ __align__(16) char smem[25088];
    int blk = blockIdx.x;
    int t = threadIdx.x;
    if (blk < 256) {
        unsigned short* Al = (unsigned short*)smem;            // 64*128 ushort = 16384 B
        unsigned short* Bl = (unsigned short*)(smem + 16384);  // 32*136 ushort = 8704 B
        int ms = blk >> 5;
        int otile = blk & 31;
        int l = t & 63, w = t >> 6;
        int kg = l >> 4, r16 = l & 15;
        f32x4 acc[2];
#pragma unroll
        for (int nt = 0; nt < 2; ++nt) acc[nt] = (f32x4){0.f, 0.f, 0.f, 0.f};

        int o_l = t & 31;
        for (int kc = 0; kc < 4; ++kc) {
            __syncthreads();
#pragma unroll
            for (int it = 0; it < 4; ++it) {
                int c = t + it * 256;
                int r = c >> 4, ch = c & 15;
                ushort8 v = *(const ushort8*)(tmem_b + (size_t)(r * 8 + ms) * 512 + kc * 128 + ch * 8);
                int sch = ch ^ (r & 7);
                *(ushort8*)(Al + r * 128 + sch * 8) = v;
            }
#pragma unroll
            for (int i = 0; i < 16; ++i) {
                int k_l = (t >> 5) + 8 * i;
                float v = Wg[((size_t)ms * 512 + kc * 128 + k_l) * 1024 + otile * 32 + o_l];
                Bl[o_l * 136 + k_l] = f2bf(v);
            }
            __syncthreads();
#pragma unroll
            for (int kk = 0; kk < 4; ++kk) {
                int ch = kk * 4 + kg;
                short8 a = *(const short8*)(Al + (w * 16 + r16) * 128 + ((ch ^ (r16 & 7)) * 8));
#pragma unroll
                for (int nt = 0; nt < 2; ++nt) {
                    short8 bfr = *(const short8*)(Bl + (nt * 16 + r16) * 136 + ch * 8);
                    acc[nt] = __builtin_amdgcn_mfma_f32_16x16x32_bf16(a, bfr, acc[nt], 0, 0, 0);
                }
            }
        }
        float ibv = ib[0], fbv = fb[0];
#pragma unroll
        for (int nt = 0; nt < 2; ++nt) {
            int o = otile * 32 + nt * 16 + r16;
            float bias = (o < 512) ? ibv : fbv;
#pragma unroll
            for (int j = 0; j < 4; ++j) {
                int b = w * 16 + kg * 4 + j;
                float g = acc[nt][j] + gate_in[b * 1024 + o] + bias;
                sg[(size_t)(b * 8 + ms) * 1024 + o] = 1.f / (1.f + expf(-g));
            }
        }
    } else {
        float* wbuf = (float*)smem;                 // 8*256 floats = 8192 B
        float* ps   = (float*)(smem + 8192);        // 8 floats
        float* red  = (float*)(smem + 8224);        // 256 floats
        int bms = blk - 256;           // b*8 + ms
        int b = bms >> 3, ms = bms & 7;

#pragma unroll
        for (int h = 0; h < 8; ++h) {
            int row = (b * 64 + h * 8 + ms) * 3;
            float acc = 0.f, psum = 0.f;
#pragma unroll
            for (int j = 0; j < 3; ++j) {
                int sj = topk_idx[row + j];
                float pj = topk_p[row + j];
                acc += pj * inputs[((size_t)b * SS + sj) * IN_ + t];
                psum += pj;
            }
            wbuf[h * 256 + t] = acc;
            if (t == 0) ps[h] = psum;
        }
        __syncthreads();

        float a_val[2];
#pragma unroll
        for (int oo = 0; oo < 2; ++oo) {
            int o = oo * 256 + t;
            int h = o >> 6;
            float acc = ps[h] * bvf[o];
            const float* wh = wbuf + h * 256;
#pragma unroll 8
            for (int i = 0; i < 256; ++i) acc += wh[i] * Wiv[i * 512 + o];
            a_val[oo] = acc;
        }

        float m0 = memory[bms * 512 + t], m1 = memory[bms * 512 + t + 256];
        float x0 = m0 + a_val[0], x1 = m1 + a_val[1];
        float mu = block_sum256(x0 + x1, red) * (1.f / 512.f);
        float d0 = x0 - mu, d1 = x1 - mu;
        float var = block_sum256(d0 * d0 + d1 * d1, red) * (1.f / 512.f);
        float rstd = rsqrtf(var + 1e-5f);
        mem1[bms * 512 + t]       = d0 * rstd * g1[t] + b1[t];
        mem1[bms * 512 + t + 256] = d1 * rstd * g1[t + 256] + b1[t + 256];
    }
}

// ---------------- K7 (MFMA): mlp x2 + LN2 + gate combine + output. 16 rows/block.
__global__ __launch_bounds__(256) void k_mlp_mfma(const float* __restrict__ mem1,
                                                  const unsigned short* __restrict__ WmlpTb,
                                                  const float* __restrict__ bmlp,
                                                  const float* __restrict__ g2,
                                                  const float* __restrict__ b2,
                                                  const float* __restrict__ sg,
                                                  const float* __restrict__ memory,
                                                  float* __restrict__ out) {
    __shared__ unsigned short At[16 * 512];
    __shared__ unsigned short Bt[16 * 512];
    __shared__ float redS[64], redQ[64], muL[16], rsL[16];
    int blk = blockIdx.x;        // 0..31
    int rowbase = blk * 16;
    int t = threadIdx.x;
    int l = t & 63, w = t >> 6;
    int kg = l >> 4, r16 = l & 15;

#pragma unroll
    for (int it = 0; it < 4; ++it) {
        int c = t + it * 256;
        int r = c >> 6, ch = c & 63;
        const float* p = mem1 + (size_t)(rowbase + r) * 512 + ch * 8;
        float4 f0 = *(const float4*)p;
        float4 f1 = *(const float4*)(p + 4);
        uint4 v;
        v.x = f2bf_pk(f0.x, f0.y);
        v.y = f2bf_pk(f0.z, f0.w);
        v.z = f2bf_pk(f1.x, f1.y);
        v.w = f2bf_pk(f1.z, f1.w);
        int sch = ch ^ (r & 7);
        *(uint4*)(At + r * 512 + sch * 8) = v;
    }
    __syncthreads();

    f32x4 acc[8];
#pragma unroll
    for (int f = 0; f < 8; ++f) acc[f] = (f32x4){0.f, 0.f, 0.f, 0.f};
    for (int kk2 = 0; kk2 < 16; ++kk2) {
        short8 a = frag_ld512(At, r16, kk2 * 4 + kg);
#pragma unroll
        for (int f = 0; f < 8; ++f) {
            short8 bfr = *(const short8*)(WmlpTb + (size_t)(w * 128 + f * 16 + r16) * 512 + kk2 * 32 + kg * 8);
            acc[f] = __builtin_amdgcn_mfma_f32_16x16x32_bf16(a, bfr, acc[f], 0, 0, 0);
        }
    }
#pragma unroll
    for (int f = 0; f < 8; ++f) {
        int o = w * 128 + f * 16 + r16;
        float bm = bmlp[o];
        int ch = o >> 3, oe = o & 7;
#pragma unroll
        for (int j = 0; j < 4; ++j) {
            int row = kg * 4 + j;
            float v = fmaxf(acc[f][j] + bm, 0.f);
            Bt[row * 512 + ((ch ^ (row & 7)) * 8 + oe)] = f2bf(v);
        }
    }
    __syncthreads();

#pragma unroll
    for (int f = 0; f < 8; ++f) acc[f] = (f32x4){0.f, 0.f, 0.f, 0.f};
    for (int kk2 = 0; kk2 < 16; ++kk2) {
        short8 a = frag_ld512(Bt, r16, kk2 * 4 + kg);
#pragma unroll
        for (int f = 0; f < 8; ++f) {
            short8 bfr = *(const short8*)(WmlpTb + (size_t)(w * 128 + f * 16 + r16) * 512 + kk2 * 32 + kg * 8);
            acc[f] = __builtin_amdgcn_mfma_f32_16x16x32_bf16(a, bfr, acc[f], 0, 0, 0);
        }
    }

    float y[8][4];
    float ps[4] = {0.f, 0.f, 0.f, 0.f}, pq[4] = {0.f, 0.f, 0.f, 0.f};
#pragma unroll
    for (int f = 0; f < 8; ++f) {
        int o = w * 128 + f * 16 + r16;
        float bm = bmlp[o];
#pragma unroll
        for (int j = 0; j < 4; ++j) {
            int row = kg * 4 + j;
            float m1v = mem1[(size_t)(rowbase + row) * 512 + o];
            float v = m1v + fmaxf(acc[f][j] + bm, 0.f);
            y[f][j] = v;
            ps[j] += v;
            pq[j] += v * v;
        }
    }
#pragma unroll
    for (int j = 0; j < 4; ++j) {
#pragma unroll
        for (int off = 1; off <= 8; off <<= 1) {
            ps[j] += __shfl_xor(ps[j], off);
            pq[j] += __shfl_xor(pq[j], off);
        }
    }
    if (r16 == 0) {
#pragma unroll
        for (int j = 0; j < 4; ++j) {
            int row = kg * 4 + j;
            redS[row * 4 + w] = ps[j];
            redQ[row * 4 + w] = pq[j];
        }
    }
    __syncthreads();
    if (t < 16) {
        float s = redS[t * 4] + redS[t * 4 + 1] + redS[t * 4 + 2] + redS[t * 4 + 3];
        float q = redQ[t * 4] + redQ[t * 4 + 1] + redQ[t * 4 + 2] + redQ[t * 4 + 3];
        float mu = s * (1.f / 512.f);
        float var = q * (1.f / 512.f) - mu * mu;
        muL[t] = mu;
        rsL[t] = rsqrtf(var + 1e-5f);
    }
    __syncthreads();

#pragma unroll
    for (int f = 0; f < 8; ++f) {
        int o = w * 128 + f * 16 + r16;
        float g2v = g2[o], b2v = b2[o];
#pragma unroll
        for (int j = 0; j < 4; ++j) {
            int row = kg * 4 + j;
            int grow = rowbase + row;
            float np = (y[f][j] - muL[row]) * rsL[row] * g2v + b2v;
            float ig = sg[(size_t)grow * 1024 + o];
            float fg = sg[(size_t)grow * 1024 + 512 + o];
            float mv = memory[(size_t)grow * 512 + o];
            out[(size_t)grow * 512 + o] = ig * tanhf(np) + fg * mv;
        }
    }
}

extern "C" void kernel_launch(void* const* d_in, const int* in_sizes, int n_in,
                              void* d_out, int out_size, void* d_ws, size_t ws_size,
                              hipStream_t stream) {
    const float* inputs = (const float*)d_in[0];
    const float* memory = (const float*)d_in[1];
    const float* Wq  = (const float*)d_in[2];
    const float* bq  = (const float*)d_in[3];
    const float* Wk  = (const float*)d_in[4];
    const float* Wv  = (const float*)d_in[6];
    const float* bv  = (const float*)d_in[7];
    const float* Wmlp= (const float*)d_in[8];
    const float* bmlp= (const float*)d_in[9];
    const float* g1  = (const float*)d_in[10];
    const float* b1  = (const float*)d_in[11];
    const float* g2  = (const float*)d_in[12];
    const float* b2  = (const float*)d_in[13];
    const float* Wi  = (const float*)d_in[14];
    const float* bi  = (const float*)d_in[15];
    const float* rw  = (const float*)d_in[16];
    const float* Wr  = (const float*)d_in[17];
    const float* br  = (const float*)d_in[18];
    const float* Wg  = (const float*)d_in[19];
    const float* fb  = (const float*)d_in[20];
    const float* ib  = (const float*)d_in[21];
    float* out = (float*)d_out;

    float* ws = (float*)d_ws;
    float* WikT   = ws + 0;                   // -> 131072
    float* Wiv    = ws + 131072;              // -> 262144
    float* bvf    = ws + 262144;              // -> 263168 (pad)
    float* qbuf   = ws + 263168;              // -> 525312
    unsigned short* Pb   = (unsigned short*)(ws + 525312);   // -> 1049600
    unsigned short* WiTf = (unsigned short*)(ws + 1049600);  // -> 1115136
    uint4* statA  = (uint4*)(ws + 1115136);   // -> 1639424
    uint4* statB  = (uint4*)(ws + 1639424);   // -> 2163712
    float* topkp  = ws + 2163712;             // -> 2176000
    int*   topki  = (int*)(ws + 2176000);     // -> 2188288
    float* giaccp = ws + 2188288;             // 64*64*512 -> 4285440
    float* gatein = ws + 4285440;             // -> 4350976
    float* sgbuf  = ws + 4350976;             // -> 4875264
    float* mem1   = ws + 4875264;             // -> 5137408
    unsigned short* tmem_b = (unsigned short*)(ws + 5137408);  // -> 5268480
    unsigned short* WmlpTb = (unsigned short*)(ws + 5268480);  // -> 5399552

    (void)in_sizes; (void)n_in; (void)out_size; (void)ws_size;

    k_pre<<<1794, 256, 0, stream>>>(Wi, Wk, Wv, bi, bv, memory, Wq, bq, Wmlp,
                                    WikT, Wiv, bvf, qbuf, WiTf, tmem_b, WmlpTb);
    k_p<<<4096, 256, 0, stream>>>(qbuf, WikT, Pb);
    k_big<<<2048, 256, 0, stream>>>(inputs, Pb, WiTf, bi, rw, statA, statB, giaccp);
    k_mid<<<1280, 256, 0, stream>>>(statA, statB, giaccp, Wr, br, topkp, topki, gatein);
    k_post<<<768, 256, 0, stream>>>(tmem_b, Wg, gatein, fb, ib, sgbuf,
                                    inputs, Wiv, bvf, topkp, topki, memory, g1, b1, mem1);
    k_mlp_mfma<<<32, 256, 0, stream>>>(mem1, WmlpTb, bmlp, g2, b2, sgbuf, memory, out);
}

// Round 17
// 253.101 us; speedup vs baseline: 1.1426x; 1.1426x over previous
//
#include <hip/hip_runtime.h>
#include <hip/hip_bf16.h>
#include <math.h>

// Problem constants
#define BB 64
#define SS 2048
#define IN_ 256
#define MSLOT 8
#define HH 8
#define HD_ 64
#define MM 512
#define NG_ 1024

typedef __attribute__((ext_vector_type(8))) short short8;
typedef __attribute__((ext_vector_type(8))) unsigned short ushort8;
typedef __attribute__((ext_vector_type(4))) unsigned short ushort4v;
typedef __attribute__((ext_vector_type(4))) float f32x4;
typedef __attribute__((ext_vector_type(16))) float f32x16;
typedef unsigned long long u64;
typedef unsigned int u32;

__device__ __forceinline__ unsigned short f2bf(float f) {
    unsigned int u = __builtin_bit_cast(unsigned int, f);
    u += 0x7fff + ((u >> 16) & 1);   // round-to-nearest-even
    return (unsigned short)(u >> 16);
}

// HW packed f32x2 -> bf16x2 (RNE), lo=a hi=b
__device__ __forceinline__ u32 f2bf_pk(float a, float b) {
    u32 r;
    asm("v_cvt_pk_bf16_f32 %0, %1, %2" : "=v"(r) : "v"(a), "v"(b));
    return r;
}

// sortable key: larger value -> larger key; equal value -> smaller idx -> larger key
__device__ __forceinline__ u64 score_key(float v, int idx) {
    u32 x = __float_as_uint(v);
    u32 fk = (x & 0x80000000u) ? ~x : (x | 0x80000000u);
    return ((u64)fk << 32) | (u32)(~(u32)idx);
}
__device__ __forceinline__ float key_val(u64 k) {
    u32 fk = (u32)(k >> 32);
    u32 x = (fk & 0x80000000u) ? (fk & 0x7FFFFFFFu) : ~fk;
    return __uint_as_float(x);
}
__device__ __forceinline__ int key_idx(u64 k) { return (int)(~(u32)k); }

__device__ __forceinline__ void merge3(u64& a0, u64& a1, u64& a2, u64 b0, u64 b1, u64 b2) {
    bool t0 = a0 >= b0;
    u64 m0 = t0 ? a0 : b0;
    u64 a0x = t0 ? a1 : a0, a1x = t0 ? a2 : a1;
    u64 b0x = t0 ? b0 : b1, b1x = t0 ? b1 : b2;
    bool t1 = a0x >= b0x;
    u64 m1 = t1 ? a0x : b0x;
    u64 a0y = t1 ? a1x : a0x;
    u64 b0y = t1 ? b0x : b1x;
    bool t2 = a0y >= b0y;
    u64 m2 = t2 ? a0y : b0y;
    a0 = m0; a1 = m1; a2 = m2;
}

__device__ __forceinline__ void merge3_shfl(u64& k0, u64& k1, u64& k2, int off) {
    u64 b0 = __shfl_xor(k0, off);
    u64 b1 = __shfl_xor(k1, off);
    u64 b2 = __shfl_xor(k2, off);
    merge3(k0, k1, k2, b0, b1, b2);
}

__device__ __forceinline__ float block_sum256(float v, float* red) {
    int t = threadIdx.x;
    red[t] = v; __syncthreads();
    for (int s = 128; s > 0; s >>= 1) {
        if (t < s) red[t] += red[t + s];
        __syncthreads();
    }
    float r = red[0];
    __syncthreads();
    return r;
}

// ---- LDS tile staging: 64 rows x 256 cols bf16, 16B-chunk XOR(r&15) swizzle
__device__ __forceinline__ void stage_tile_f32cvt(unsigned short* lds,
                                                  const float* __restrict__ src,
                                                  int t) {
#pragma unroll
    for (int it = 0; it < 8; ++it) {
        int c = t + it * 256;
        int r = c >> 5, ch = c & 31;
        const float* p = src + (size_t)r * 256 + ch * 8;
        float4 f0 = *(const float4*)p;
        float4 f1 = *(const float4*)(p + 4);
        uint4 v;
        v.x = f2bf_pk(f0.x, f0.y);
        v.y = f2bf_pk(f0.z, f0.w);
        v.z = f2bf_pk(f1.x, f1.y);
        v.w = f2bf_pk(f1.z, f1.w);
        int sch = ch ^ (r & 15);
        *(uint4*)(lds + r * 256 + sch * 8) = v;
    }
}

__device__ __forceinline__ short8 frag_ld(const unsigned short* lds, int row, int chunk) {
    int sch = chunk ^ (row & 15);
    return *(const short8*)(lds + row * 256 + sch * 8);
}

__device__ __forceinline__ short8 frag_ld512(const unsigned short* lds, int row, int chunk) {
    int sch = chunk ^ (row & 7);
    return *(const short8*)(lds + row * 512 + sch * 8);
}

// ---------------- K_PRE: fused weights GEMM + q GEMM + repacks (independent prep work)
__global__ __launch_bounds__(256) void k_pre(const float* __restrict__ Wi,
                                             const float* __restrict__ Wk,
                                             const float* __restrict__ Wv,
                                             const float* __restrict__ bi,
                                             const float* __restrict__ bv,
                                             const float* __restrict__ memory,
                                             const float* __restrict__ Wq,
                                             const float* __restrict__ bq,
                                             const float* __restrict__ Wmlp,
                                             float* __restrict__ WikT,
                                             float* __restrict__ Wiv,
                                             float* __restrict__ bvf,
                                             float* __restrict__ q,
                                             unsigned short* __restrict__ WiTf,
                                             unsigned short* __restrict__ tm,
                                             unsigned short* __restrict__ WmlpTb) {
    __shared__ float As[64 * 33];   // 2112 floats
    __shared__ float Bs[32 * 65];   // 2080 floats
    int blk = blockIdx.x;
    int t = threadIdx.x;

    if (blk < 256) {
        // fused-weights GEMM: WikT / Wiv
        int which = blk >> 7;
        int rem = blk & 127;
        int ot = rem >> 3, it = rem & 7;
        int o0 = ot * 32, i0 = it * 32;
        const float* W = which ? Wv : Wk;
        int tx = t & 15, ty = t >> 4;
        float acc[2][2] = {{0.f, 0.f}, {0.f, 0.f}};
        for (int jc = 0; jc < 512; jc += 64) {
            __syncthreads();
#pragma unroll
            for (int k = 0; k < 8; ++k) {
                int idx = t + k * 256;
                int jl = idx >> 5, ol = idx & 31;
                As[jl * 33 + ol] = W[(jc + jl) * 512 + o0 + ol];
            }
#pragma unroll
            for (int k = 0; k < 8; ++k) {
                int idx = t + k * 256;
                int il = idx >> 6, jl = idx & 63;
                Bs[il * 65 + jl] = Wi[(i0 + il) * 512 + jc + jl];
            }
            __syncthreads();
#pragma unroll 4
            for (int jl = 0; jl < 64; ++jl) {
                float a0 = As[jl * 33 + ty], a1 = As[jl * 33 + ty + 16];
                float b0 = Bs[tx * 65 + jl], b1 = Bs[(tx + 16) * 65 + jl];
                acc[0][0] += a0 * b0; acc[0][1] += a0 * b1;
                acc[1][0] += a1 * b0; acc[1][1] += a1 * b1;
            }
        }
#pragma unroll
        for (int m = 0; m < 2; ++m)
#pragma unroll
            for (int n = 0; n < 2; ++n) {
                int o = o0 + ty + 16 * m, i = i0 + tx + 16 * n;
                if (which) Wiv[i * 512 + o] = acc[m][n];
                else       WikT[o * 256 + i] = acc[m][n];
            }
    } else if (blk < 258) {
        int o = (blk - 256) * 256 + t;
        float acc = bv[o];
        for (int j = 0; j < 512; ++j) acc += bi[j] * Wv[j * 512 + o];
        bvf[o] = acc;
    } else if (blk < 514) {
        // q GEMM: q = memory@Wq + bq. Am -> Bs (32*65), Bq -> As (64*33)
        int qb = blk - 258;
        int bt = qb >> 4, ot2 = qb & 15;
        int b0 = bt * 32, o0 = ot2 * 32;
        int tx = t & 15, ty = t >> 4;
        float acc[2][2] = {{0.f, 0.f}, {0.f, 0.f}};
        for (int jc = 0; jc < 512; jc += 64) {
            __syncthreads();
#pragma unroll
            for (int k = 0; k < 8; ++k) {
                int idx = t + k * 256;
                int bl = idx >> 6, jl = idx & 63;
                Bs[bl * 65 + jl] = memory[(b0 + bl) * 512 + jc + jl];
            }
#pragma unroll
            for (int k = 0; k < 8; ++k) {
                int idx = t + k * 256;
                int jl = idx >> 5, ol = idx & 31;
                As[jl * 33 + ol] = Wq[(jc + jl) * 512 + o0 + ol];
            }
            __syncthreads();
#pragma unroll 4
            for (int jl = 0; jl < 64; ++jl) {
                float a0 = Bs[ty * 65 + jl], a1 = Bs[(ty + 16) * 65 + jl];
                float b0v = As[jl * 33 + tx], b1v = As[jl * 33 + tx + 16];
                acc[0][0] += a0 * b0v; acc[0][1] += a0 * b1v;
                acc[1][0] += a1 * b0v; acc[1][1] += a1 * b1v;
            }
        }
#pragma unroll
        for (int m = 0; m < 2; ++m)
#pragma unroll
            for (int n = 0; n < 2; ++n) {
                int bms = b0 + ty + 16 * m, o = o0 + tx + 16 * n;
                q[bms * 512 + o] = acc[m][n] + bq[o];
            }
    } else {
        int pb = blk - 514;
        if (pb < 512) {
            int idx = pb * 256 + t;
            int e = idx & 7, l = (idx >> 3) & 63, ks = (idx >> 9) & 15, dtg = idx >> 13;
            int d = dtg * 32 + (l & 31);
            int k = ks * 16 + (l >> 5) * 8 + e;
            WiTf[idx] = f2bf(Wi[k * 512 + d]);
        } else if (pb < 768) {
            int i = ((pb - 512) * 256 + t) * 4;
            float4 v = *(const float4*)(memory + i);
            ushort4v o;
            o[0] = f2bf(tanhf(v.x)); o[1] = f2bf(tanhf(v.y));
            o[2] = f2bf(tanhf(v.z)); o[3] = f2bf(tanhf(v.w));
            *(ushort4v*)(tm + i) = o;
        } else {
            int o = pb - 768;   // 0..511
#pragma unroll
            for (int kk = 0; kk < 2; ++kk) {
                int k = kk * 256 + t;
                WmlpTb[o * 512 + k] = f2bf(Wmlp[k * 512 + o]);
            }
        }
    }
}

// ---------------- K1c: P[b,hm,i] (bf16)
__global__ __launch_bounds__(256) void k_p(const float* __restrict__ q,
                                           const float* __restrict__ WikT,
                                           unsigned short* __restrict__ Pb) {
    int blk = blockIdx.x;           // b*64 + hm
    int b = blk >> 6, hm = blk & 63;
    int h = hm >> 3, ms = hm & 7;
    int t = threadIdx.x;
    __shared__ float qv[64];
    if (t < 64) qv[t] = q[(b * 8 + ms) * 512 + h * 64 + t];
    __syncthreads();
    float acc = 0.f;
    for (int d = 0; d < 64; ++d) acc += qv[d] * WikT[(h * 64 + d) * 256 + t];
    Pb[blk * 256 + t] = f2bf(acc);
}

// ---------------- K_BIG v10: gimean first, scores second; Sl overlays Il (32.8 KB LDS).
// stage -> gimean -> scores (acc live) -> barrier -> stash -> barrier -> stats.
__global__ __launch_bounds__(256, 3) void k_big(const float* __restrict__ inputs,
                                                const unsigned short* __restrict__ Pb,
                                                const unsigned short* __restrict__ WiTf,
                                                const float* __restrict__ bi,
                                                const float* __restrict__ rw,
                                                uint4* __restrict__ statA,
                                                uint4* __restrict__ statB,
                                                float* __restrict__ giaccp) {
    __shared__ unsigned short Il[64 * 256];   // 32 KB; Sl overlays after all Il reads
    float* Sl = (float*)Il;                   // [64][65] f32 score stash (16.6 KB)
    int t = threadIdx.x;
    int hw = blockIdx.x;                      // 0..2047
    int L = (hw & 7) * 256 + (hw >> 3);
    int b = L >> 5, stile = L & 31;
    int l = t & 63, w = t >> 6;
    int l31 = l & 31, hi = l >> 5;
    int sh = w & 1, dh = w >> 1;

    stage_tile_f32cvt(Il, inputs + ((size_t)b * SS + stile * 64) * IN_, t);
    __syncthreads();

    // ---- gimean (32x32x16): A = Il frags, B = WiTf (d cols). One dtg per grp, 2 chains.
#pragma unroll 1
    for (int grp = 0; grp < 8; ++grp) {
        int dtg = dh * 8 + grp;
        f32x16 ga = {0.f,0.f,0.f,0.f,0.f,0.f,0.f,0.f,0.f,0.f,0.f,0.f,0.f,0.f,0.f,0.f};
        f32x16 gb = {0.f,0.f,0.f,0.f,0.f,0.f,0.f,0.f,0.f,0.f,0.f,0.f,0.f,0.f,0.f,0.f};
#pragma unroll
        for (int ks = 0; ks < 8; ++ks) {
            short8 il0 = frag_ld(Il, sh * 32 + l31, ks * 2 + hi);
            short8 wf0 = *(const short8*)(WiTf + ((size_t)(dtg * 16 + ks) * 64 + l) * 8);
            ga = __builtin_amdgcn_mfma_f32_32x32x16_bf16(il0, wf0, ga, 0, 0, 0);
            short8 il1 = frag_ld(Il, sh * 32 + l31, (ks + 8) * 2 + hi);
            short8 wf1 = *(const short8*)(WiTf + ((size_t)(dtg * 16 + ks + 8) * 64 + l) * 8);
            gb = __builtin_amdgcn_mfma_f32_32x32x16_bf16(il1, wf1, gb, 0, 0, 0);
        }
        int d = dtg * 32 + l31;
        float bid = bi[d], rwd = rw[d];
        float rs = 0.f;
#pragma unroll
        for (int r = 0; r < 16; ++r)
            rs += fmaxf(rwd * (ga[r] + gb[r] + bid), 0.f);
        rs += __shfl_xor(rs, 32);
        if (hi == 0)
            giaccp[((size_t)(stile * 2 + sh) * 64 + b) * 512 + d] = rs;
    }

    // ---- scores (32x32x16): A = P rows (hm = dh*32+l31, L2), B = Il frags. 2x8 chains.
    f32x16 s0 = {0.f,0.f,0.f,0.f,0.f,0.f,0.f,0.f,0.f,0.f,0.f,0.f,0.f,0.f,0.f,0.f};
    f32x16 s1 = {0.f,0.f,0.f,0.f,0.f,0.f,0.f,0.f,0.f,0.f,0.f,0.f,0.f,0.f,0.f,0.f};
    {
        const unsigned short* pbase = Pb + ((size_t)(b * 64 + dh * 32 + l31)) * 256;
#pragma unroll
        for (int ks = 0; ks < 8; ++ks) {
            short8 pf0 = *(const short8*)(pbase + ks * 16 + hi * 8);
            short8 il0 = frag_ld(Il, sh * 32 + l31, ks * 2 + hi);
            s0 = __builtin_amdgcn_mfma_f32_32x32x16_bf16(pf0, il0, s0, 0, 0, 0);
            short8 pf1 = *(const short8*)(pbase + (ks + 8) * 16 + hi * 8);
            short8 il1 = frag_ld(Il, sh * 32 + l31, (ks + 8) * 2 + hi);
            s1 = __builtin_amdgcn_mfma_f32_32x32x16_bf16(pf1, il1, s1, 0, 0, 0);
        }
    }
    __syncthreads();   // all Il fragment reads complete

    // ---- stash scores into Sl (overlaying Il): row = (r&3)+8*(r>>2)+4*hi, col = sh*32+l31
#pragma unroll
    for (int r = 0; r < 16; ++r) {
        int hm = dh * 32 + (r & 3) + 8 * (r >> 2) + 4 * hi;
        Sl[hm * 65 + sh * 32 + l31] = s0[r] + s1[r];
    }
    __syncthreads();

    // ---- stats: thread t -> row = t>>2, s-chunk (t&3)*16..+15
    int row = t >> 2, cq = t & 3;
    float v[16];
#pragma unroll
    for (int i = 0; i < 16; ++i) v[i] = Sl[row * 65 + cq * 16 + i];

    u64 k0 = 0, k1 = 0, k2 = 0;
#pragma unroll
    for (int i = 0; i < 16; ++i) {
        u64 key = score_key(v[i], stile * 64 + cq * 16 + i);
        bool g0 = key > k0, g1 = key > k1, g2 = key > k2;
        k2 = g1 ? k1 : (g2 ? key : k2);
        k1 = g0 ? k0 : (g1 ? key : k1);
        k0 = g0 ? key : k0;
    }
    merge3_shfl(k0, k1, k2, 1);
    merge3_shfl(k0, k1, k2, 2);

    float m = key_val(k0);
    float se = 0.f;
#pragma unroll
    for (int i = 0; i < 16; ++i) se += expf(v[i] - m);
    se += __shfl_xor(se, 1);
    se += __shfl_xor(se, 2);

    if (cq == 0) {
        int grow = (b * 64 + row) * 32 + stile;
        statA[grow] = make_uint4(__float_as_uint(se), (u32)(k0 >> 32), (u32)k0, (u32)(k1 >> 32));
        statB[grow] = make_uint4((u32)k1, (u32)(k2 >> 32), (u32)k2, 0u);
    }
}

// ---------------- K_MID: combine (blocks 0..1023) + gatein (1024..1279)
__global__ __launch_bounds__(256) void k_mid(const uint4* __restrict__ statA,
                                             const uint4* __restrict__ statB,
                                             const float* __restrict__ giaccp,
                                             const float* __restrict__ Wr,
                                             const float* __restrict__ br,
                                             float* __restrict__ topk_p,
                                             int* __restrict__ topk_idx,
                                             float* __restrict__ gate_in) {
    __shared__ float gm[512];
    int blk = blockIdx.x;
    int t = threadIdx.x;
    if (blk < 1024) {
        int row = blk * 4 + (t >> 6);
        int l = t & 63;
        float s_c = 0.f, m_c = 0.f;
        u64 k0 = 0, k1 = 0, k2 = 0;
        if (l < 32) {
            uint4 A = statA[row * 32 + l];
            uint4 Bv = statB[row * 32 + l];
            s_c = __uint_as_float(A.x);
            k0 = ((u64)A.y << 32) | A.z;
            k1 = ((u64)A.w << 32) | Bv.x;
            k2 = ((u64)Bv.y << 32) | Bv.z;
            m_c = key_val(k0);
        }
        merge3_shfl(k0, k1, k2, 1);
        merge3_shfl(k0, k1, k2, 2);
        merge3_shfl(k0, k1, k2, 4);
        merge3_shfl(k0, k1, k2, 8);
        merge3_shfl(k0, k1, k2, 16);

        float M = key_val(k0);
        float S = (l < 32) ? s_c * expf(m_c - M) : 0.f;
#pragma unroll
        for (int off = 1; off <= 16; off <<= 1) S += __shfl_xor(S, off);

        if (l == 0) {
            u64 ks[3] = {k0, k1, k2};
#pragma unroll
            for (int r = 0; r < 3; ++r) {
                topk_p[row * 3 + r] = expf(key_val(ks[r]) - M) / S;
                topk_idx[row * 3 + r] = key_idx(ks[r]);
            }
        }
    } else {
        int gb = blk - 1024;
        int b = gb >> 2, ot = gb & 3;
        int o = ot * 256 + t;
        float s0 = 0.f, s1 = 0.f;
        for (int st = 0; st < 64; ++st) {
            s0 += giaccp[((size_t)st * 64 + b) * 512 + t];
            s1 += giaccp[((size_t)st * 64 + b) * 512 + t + 256];
        }
        gm[t]       = s0 * (1.0f / 2048.0f);
        gm[t + 256] = s1 * (1.0f / 2048.0f);
        __syncthreads();
        float acc = br[o];
#pragma unroll 8
        for (int d = 0; d < 512; ++d) acc += gm[d] * Wr[d * 1024 + o];
        gate_in[b * 1024 + o] = acc;
    }
}

// ---------------- K_POST: gates MFMA (blocks 0..255) + att+LN1 (256..767)
__global__ __launch_bounds__(256) void k_post(const unsigned short* __restrict__ tmem_b,
                                              const float* __restrict__ Wg,
                                              const float* __restrict__ gate_in,
                                              const float* __restrict__ fb,
                                              const float* __restrict__ ib,
                                              float* __restrict__ sg,
                                              const float* __restrict__ inputs,
                                              const float* __restrict__ Wiv,
                                              const float* __restrict__ bvf,
                                              const float* __restrict__ topk_p,
                                              const int* __restrict__ topk_idx,
                                              const float* __restrict__ memory,
                                              const float* __restrict__ g1,
                                              const float* __restrict__ b1,
                                              float* __restrict__ mem1) {
    __shared__ __align__(16) char smem[25088];
    int blk = blockIdx.x;
    int t = threadIdx.x;
    if (blk < 256) {
        unsigned short* Al = (unsigned short*)smem;            // 64*128 ushort = 16384 B
        unsigned short* Bl = (unsigned short*)(smem + 16384);  // 32*136 ushort = 8704 B
        int ms = blk >> 5;
        int otile = blk & 31;
        int l = t & 63, w = t >> 6;
        int kg = l >> 4, r16 = l & 15;
        f32x4 acc[2];
#pragma unroll
        for (int nt = 0; nt < 2; ++nt) acc[nt] = (f32x4){0.f, 0.f, 0.f, 0.f};

        int o_l = t & 31;
        for (int kc = 0; kc < 4; ++kc) {
            __syncthreads();
#pragma unroll
            for (int it = 0; it < 4; ++it) {
                int c = t + it * 256;
                int r = c >> 4, ch = c & 15;
                ushort8 v = *(const ushort8*)(tmem_b + (size_t)(r * 8 + ms) * 512 + kc * 128 + ch * 8);
                int sch = ch ^ (r & 7);
                *(ushort8*)(Al + r * 128 + sch * 8) = v;
            }
#pragma unroll
            for (int i = 0; i < 16; ++i) {
                int k_l = (t >> 5) + 8 * i;
                float v = Wg[((size_t)ms * 512 + kc * 128 + k_l) * 1024 + otile * 32 + o_l];
                Bl[o_l * 136 + k_l] = f2bf(v);
            }
            __syncthreads();
#pragma unroll
            for (int kk = 0; kk < 4; ++kk) {
                int ch = kk * 4 + kg;
                short8 a = *(const short8*)(Al + (w * 16 + r16) * 128 + ((ch ^ (r16 & 7)) * 8));
#pragma unroll
                for (int nt = 0; nt < 2; ++nt) {
                    short8 bfr = *(const short8*)(Bl + (nt * 16 + r16) * 136 + ch * 8);
                    acc[nt] = __builtin_amdgcn_mfma_f32_16x16x32_bf16(a, bfr, acc[nt], 0, 0, 0);
                }
            }
        }
        float ibv = ib[0], fbv = fb[0];
#pragma unroll
        for (int nt = 0; nt < 2; ++nt) {
            int o = otile * 32 + nt * 16 + r16;
            float bias = (o < 512) ? ibv : fbv;
#pragma unroll
            for (int j = 0; j < 4; ++j) {
                int b = w * 16 + kg * 4 + j;
                float g = acc[nt][j] + gate_in[b * 1024 + o] + bias;
                sg[(size_t)(b * 8 + ms) * 1024 + o] = 1.f / (1.f + expf(-g));
            }
        }
    } else {
        float* wbuf = (float*)smem;                 // 8*256 floats = 8192 B
        float* ps   = (float*)(smem + 8192);        // 8 floats
        float* red  = (float*)(smem + 8224);        // 256 floats
        int bms = blk - 256;           // b*8 + ms
        int b = bms >> 3, ms = bms & 7;

#pragma unroll
        for (int h = 0; h < 8; ++h) {
            int row = (b * 64 + h * 8 + ms) * 3;
            float acc = 0.f, psum = 0.f;
#pragma unroll
            for (int j = 0; j < 3; ++j) {
                int sj = topk_idx[row + j];
                float pj = topk_p[row + j];
                acc += pj * inputs[((size_t)b * SS + sj) * IN_ + t];
                psum += pj;
            }
            wbuf[h * 256 + t] = acc;
            if (t == 0) ps[h] = psum;
        }
        __syncthreads();

        float a_val[2];
#pragma unroll
        for (int oo = 0; oo < 2; ++oo) {
            int o = oo * 256 + t;
            int h = o >> 6;
            float acc = ps[h] * bvf[o];
            const float* wh = wbuf + h * 256;
#pragma unroll 8
            for (int i = 0; i < 256; ++i) acc += wh[i] * Wiv[i * 512 + o];
            a_val[oo] = acc;
        }

        float m0 = memory[bms * 512 + t], m1 = memory[bms * 512 + t + 256];
        float x0 = m0 + a_val[0], x1 = m1 + a_val[1];
        float mu = block_sum256(x0 + x1, red) * (1.f / 512.f);
        float d0 = x0 - mu, d1 = x1 - mu;
        float var = block_sum256(d0 * d0 + d1 * d1, red) * (1.f / 512.f);
        float rstd = rsqrtf(var + 1e-5f);
        mem1[bms * 512 + t]       = d0 * rstd * g1[t] + b1[t];
        mem1[bms * 512 + t + 256] = d1 * rstd * g1[t + 256] + b1[t + 256];
    }
}

// ---------------- K7 (MFMA): mlp x2 + LN2 + gate combine + output. 16 rows/block.
__global__ __launch_bounds__(256) void k_mlp_mfma(const float* __restrict__ mem1,
                                                  const unsigned short* __restrict__ WmlpTb,
                                                  const float* __restrict__ bmlp,
                                                  const float* __restrict__ g2,
                                                  const float* __restrict__ b2,
                                                  const float* __restrict__ sg,
                                                  const float* __restrict__ memory,
                                                  float* __restrict__ out) {
    __shared__ unsigned short At[16 * 512];
    __shared__ unsigned short Bt[16 * 512];
    __shared__ float redS[64], redQ[64], muL[16], rsL[16];
    int blk = blockIdx.x;        // 0..31
    int rowbase = blk * 16;
    int t = threadIdx.x;
    int l = t & 63, w = t >> 6;
    int kg = l >> 4, r16 = l & 15;

#pragma unroll
    for (int it = 0; it < 4; ++it) {
        int c = t + it * 256;
        int r = c >> 6, ch = c & 63;
        const float* p = mem1 + (size_t)(rowbase + r) * 512 + ch * 8;
        float4 f0 = *(const float4*)p;
        float4 f1 = *(const float4*)(p + 4);
        uint4 v;
        v.x = f2bf_pk(f0.x, f0.y);
        v.y = f2bf_pk(f0.z, f0.w);
        v.z = f2bf_pk(f1.x, f1.y);
        v.w = f2bf_pk(f1.z, f1.w);
        int sch = ch ^ (r & 7);
        *(uint4*)(At + r * 512 + sch * 8) = v;
    }
    __syncthreads();

    f32x4 acc[8];
#pragma unroll
    for (int f = 0; f < 8; ++f) acc[f] = (f32x4){0.f, 0.f, 0.f, 0.f};
    for (int kk2 = 0; kk2 < 16; ++kk2) {
        short8 a = frag_ld512(At, r16, kk2 * 4 + kg);
#pragma unroll
        for (int f = 0; f < 8; ++f) {
            short8 bfr = *(const short8*)(WmlpTb + (size_t)(w * 128 + f * 16 + r16) * 512 + kk2 * 32 + kg * 8);
            acc[f] = __builtin_amdgcn_mfma_f32_16x16x32_bf16(a, bfr, acc[f], 0, 0, 0);
        }
    }
#pragma unroll
    for (int f = 0; f < 8; ++f) {
        int o = w * 128 + f * 16 + r16;
        float bm = bmlp[o];
        int ch = o >> 3, oe = o & 7;
#pragma unroll
        for (int j = 0; j < 4; ++j) {
            int row = kg * 4 + j;
            float v = fmaxf(acc[f][j] + bm, 0.f);
            Bt[row * 512 + ((ch ^ (row & 7)) * 8 + oe)] = f2bf(v);
        }
    }
    __syncthreads();

#pragma unroll
    for (int f = 0; f < 8; ++f) acc[f] = (f32x4){0.f, 0.f, 0.f, 0.f};
    for (int kk2 = 0; kk2 < 16; ++kk2) {
        short8 a = frag_ld512(Bt, r16, kk2 * 4 + kg);
#pragma unroll
        for (int f = 0; f < 8; ++f) {
            short8 bfr = *(const short8*)(WmlpTb + (size_t)(w * 128 + f * 16 + r16) * 512 + kk2 * 32 + kg * 8);
            acc[f] = __builtin_amdgcn_mfma_f32_16x16x32_bf16(a, bfr, acc[f], 0, 0, 0);
        }
    }

    float y[8][4];
    float ps[4] = {0.f, 0.f, 0.f, 0.f}, pq[4] = {0.f, 0.f, 0.f, 0.f};
#pragma unroll
    for (int f = 0; f < 8; ++f) {
        int o = w * 128 + f * 16 + r16;
        float bm = bmlp[o];
#pragma unroll
        for (int j = 0; j < 4; ++j) {
            int row = kg * 4 + j;
            float m1v = mem1[(size_t)(rowbase + row) * 512 + o];
            float v = m1v + fmaxf(acc[f][j] + bm, 0.f);
            y[f][j] = v;
            ps[j] += v;
            pq[j] += v * v;
        }
    }
#pragma unroll
    for (int j = 0; j < 4; ++j) {
#pragma unroll
        for (int off = 1; off <= 8; off <<= 1) {
            ps[j] += __shfl_xor(ps[j], off);
            pq[j] += __shfl_xor(pq[j], off);
        }
    }
    if (r16 == 0) {
#pragma unroll
        for (int j = 0; j < 4; ++j) {
            int row = kg * 4 + j;
            redS[row * 4 + w] = ps[j];
            redQ[row * 4 + w] = pq[j];
        }
    }
    __syncthreads();
    if (t < 16) {
        float s = redS[t * 4] + redS[t * 4 + 1] + redS[t * 4 + 2] + redS[t * 4 + 3];
        float q = redQ[t * 4] + redQ[t * 4 + 1] + redQ[t * 4 + 2] + redQ[t * 4 + 3];
        float mu = s * (1.f / 512.f);
        float var = q * (1.f / 512.f) - mu * mu;
        muL[t] = mu;
        rsL[t] = rsqrtf(var + 1e-5f);
    }
    __syncthreads();

#pragma unroll
    for (int f = 0; f < 8; ++f) {
        int o = w * 128 + f * 16 + r16;
        float g2v = g2[o], b2v = b2[o];
#pragma unroll
        for (int j = 0; j < 4; ++j) {
            int row = kg * 4 + j;
            int grow = rowbase + row;
            float np = (y[f][j] - muL[row]) * rsL[row] * g2v + b2v;
            float ig = sg[(size_t)grow * 1024 + o];
            float fg = sg[(size_t)grow * 1024 + 512 + o];
            float mv = memory[(size_t)grow * 512 + o];
            out[(size_t)grow * 512 + o] = ig * tanhf(np) + fg * mv;
        }
    }
}

extern "C" void kernel_launch(void* const* d_in, const int* in_sizes, int n_in,
                              void* d_out, int out_size, void* d_ws, size_t ws_size,
                              hipStream_t stream) {
    const float* inputs = (const float*)d_in[0];
    const float* memory = (const float*)d_in[1];
    const float* Wq  = (const float*)d_in[2];
    const float* bq  = (const float*)d_in[3];
    const float* Wk  = (const float*)d_in[4];
    const float* Wv  = (const float*)d_in[6];
    const float* bv  = (const float*)d_in[7];
    const float* Wmlp= (const float*)d_in[8];
    const float* bmlp= (const float*)d_in[9];
    const float* g1  = (const float*)d_in[10];
    const float* b1  = (const float*)d_in[11];
    const float* g2  = (const float*)d_in[12];
    const float* b2  = (const float*)d_in[13];
    const float* Wi  = (const float*)d_in[14];
    const float* bi  = (const float*)d_in[15];
    const float* rw  = (const float*)d_in[16];
    const float* Wr  = (const float*)d_in[17];
    const float* br  = (const float*)d_in[18];
    const float* Wg  = (const float*)d_in[19];
    const float* fb  = (const float*)d_in[20];
    const float* ib  = (const float*)d_in[21];
    float* out = (float*)d_out;

    float* ws = (float*)d_ws;
    float* WikT   = ws + 0;                   // -> 131072
    float* Wiv    = ws + 131072;              // -> 262144
    float* bvf    = ws + 262144;              // -> 263168 (pad)
    float* qbuf   = ws + 263168;              // -> 525312
    unsigned short* Pb   = (unsigned short*)(ws + 525312);   // -> 1049600
    unsigned short* WiTf = (unsigned short*)(ws + 1049600);  // -> 1115136
    uint4* statA  = (uint4*)(ws + 1115136);   // -> 1639424
    uint4* statB  = (uint4*)(ws + 1639424);   // -> 2163712
    float* topkp  = ws + 2163712;             // -> 2176000
    int*   topki  = (int*)(ws + 2176000);     // -> 2188288
    float* giaccp = ws + 2188288;             // 64*64*512 -> 4285440
    float* gatein = ws + 4285440;             // -> 4350976
    float* sgbuf  = ws + 4350976;             // -> 4875264
    float* mem1   = ws + 4875264;             // -> 5137408
    unsigned short* tmem_b = (unsigned short*)(ws + 5137408);  // -> 5268480
    unsigned short* WmlpTb = (unsigned short*)(ws + 5268480);  // -> 5399552

    (void)in_sizes; (void)n_in; (void)out_size; (void)ws_size;

    k_pre<<<1794, 256, 0, stream>>>(Wi, Wk, Wv, bi, bv, memory, Wq, bq, Wmlp,
                                    WikT, Wiv, bvf, qbuf, WiTf, tmem_b, WmlpTb);
    k_p<<<4096, 256, 0, stream>>>(qbuf, WikT, Pb);
    k_big<<<2048, 256, 0, stream>>>(inputs, Pb, WiTf, bi, rw, statA, statB, giaccp);
    k_mid<<<1280, 256, 0, stream>>>(statA, statB, giaccp, Wr, br, topkp, topki, gatein);
    k_post<<<768, 256, 0, stream>>>(tmem_b, Wg, gatein, fb, ib, sgbuf,
                                    inputs, Wiv, bvf, topkp, topki, memory, g1, b1, mem1);
    k_mlp_mfma<<<32, 256, 0, stream>>>(mem1, WmlpTb, bmlp, g2, b2, sgbuf, memory, out);
}